// Round 13
// baseline (786.676 us; speedup 1.0000x reference)
//
#include <hip/hip_runtime.h>
#include <hip/hip_bf16.h>
#include <math.h>

#define EPSF 1e-6f
#define NLBL 159
#define NLP  160
#define HID  1024
#define BATCH 8192
#define MROWS 32
#define PBS  168   // ushort row stride p1b
#define SBS  1044  // ushort row stride s_b (522 dw = 10 mod 32 -> conflict-free)
#define K1   1836
#define K1P  1856
#define NF   150
#define NFP  160

typedef __attribute__((ext_vector_type(8))) short short8v;
typedef __attribute__((ext_vector_type(4))) float f32x4;

__device__ inline ushort f2bf(float f) {
  __hip_bfloat16 h = __float2bfloat16(f);
  return *reinterpret_cast<ushort*>(&h);
}
__device__ inline float bf2f(ushort u) {
  unsigned v = ((unsigned)u) << 16;
  return __uint_as_float(v);
}
__device__ inline float rcpf(float x) { return __builtin_amdgcn_rcpf(x); }
__device__ inline float sigmoidf(float x) { return rcpf(1.0f + __expf(-x)); }

// async global->LDS DMA, 16B per lane (wave-uniform LDS base + lane*16)
__device__ __forceinline__ void dma16(const void* g, void* l) {
  __builtin_amdgcn_global_load_lds(
      (const __attribute__((address_space(1))) unsigned int*)g,
      (__attribute__((address_space(3))) unsigned int*)l, 16, 0, 0);
}

// ---------------- threefry2x32 (exact jax semantics, 20 rounds) ----------------
__device__ inline unsigned rotl32(unsigned x, int d){ return (x<<d)|(x>>(32-d)); }

__device__ inline void threefry2x32(unsigned k0, unsigned k1,
                                    unsigned x0, unsigned x1,
                                    unsigned* o0, unsigned* o1) {
  unsigned ks0=k0, ks1=k1, ks2=k0^k1^0x1BD11BDAu;
  x0 += ks0; x1 += ks1;
#define TF_R(r) { x0 += x1; x1 = rotl32(x1,(r)); x1 ^= x0; }
  TF_R(13) TF_R(15) TF_R(26) TF_R(6)  x0 += ks1; x1 += ks2 + 1u;
  TF_R(17) TF_R(29) TF_R(16) TF_R(24) x0 += ks2; x1 += ks0 + 2u;
  TF_R(13) TF_R(15) TF_R(26) TF_R(6)  x0 += ks0; x1 += ks1 + 3u;
  TF_R(17) TF_R(29) TF_R(16) TF_R(24) x0 += ks1; x1 += ks2 + 4u;
  TF_R(13) TF_R(15) TF_R(26) TF_R(6)  x0 += ks2; x1 += ks0 + 5u;
#undef TF_R
  *o0 = x0; *o1 = x1;
}

// ---------------- generic f32 GEMM: C = act(A(MxK) @ W(NxK)^T + bias) ----------------
template<int RELU>
__global__ __launch_bounds__(256) void gemm_xwt(const float* __restrict__ A,
                                                const float* __restrict__ W,
                                                const float* __restrict__ bias,
                                                float* __restrict__ C,
                                                int M, int N, int K) {
  __shared__ float As[32][68];
  __shared__ float Ws[32][68];
  const int tid = threadIdx.x;
  const int m0 = blockIdx.x * 64;
  const int n0 = blockIdx.y * 64;
  const int tn = tid & 15;
  const int tm = tid >> 4;
  float acc[4][4];
#pragma unroll
  for (int i=0;i<4;++i)
#pragma unroll
    for (int j=0;j<4;++j) acc[i][j]=0.f;

  for (int k0 = 0; k0 < K; k0 += 32) {
    __syncthreads();
#pragma unroll
    for (int s2 = 0; s2 < 8; ++s2) {
      int f = tid + s2*256;
      int kk = f & 31, mm = f >> 5;
      int k = k0 + kk;
      float av = 0.f, wvv = 0.f;
      if (k < K) {
        av = A[(size_t)(m0+mm)*K + k];
        int n = n0 + mm;
        if (n < N) wvv = W[(size_t)n*K + k];
      }
      As[kk][mm] = av;
      Ws[kk][mm] = wvv;
    }
    __syncthreads();
    for (int kk=0; kk<32; ++kk) {
      float4 a4 = *(const float4*)&As[kk][tm*4];
      float4 b4 = *(const float4*)&Ws[kk][tn*4];
      float ai[4] = {a4.x,a4.y,a4.z,a4.w};
      float bj[4] = {b4.x,b4.y,b4.z,b4.w};
#pragma unroll
      for (int i=0;i<4;++i)
#pragma unroll
        for (int j=0;j<4;++j) acc[i][j] = fmaf(ai[i], bj[j], acc[i][j]);
    }
  }
#pragma unroll
  for (int i=0;i<4;++i)
#pragma unroll
    for (int j=0;j<4;++j) {
      int m = m0 + tm*4 + i;
      int n = n0 + tn*4 + j;
      if (n < N) {
        float v = acc[i][j] + bias[n];
        if (RELU) v = fmaxf(v, 0.f);
        C[(size_t)m*N + n] = v;
      }
    }
}

// ---------------- prep: Wg1 (1024x159 f32) -> Wg1b[1024][160] bf16, Wg1Tb[160][1024] bf16 ----------------
__global__ void prep_weights(const float* __restrict__ Wg1,
                             ushort* __restrict__ Wg1b,
                             ushort* __restrict__ Wg1Tb) {
  int idx = blockIdx.x*256 + threadIdx.x;
  if (idx >= HID*NLP) return;
  int h = idx / NLP, l = idx % NLP;
  float v = (l < NLBL) ? Wg1[h*NLBL + l] : 0.f;
  ushort b = f2bf(v);
  Wg1b[h*NLP + l]  = b;
  Wg1Tb[l*HID + h] = b;
}

// ---------------- prep: Wf1 (150x1836 f32) -> split hi/lo bf16, padded [160][1856] ----------------
__global__ void prep_wf1(const float* __restrict__ Wf1,
                         ushort* __restrict__ Wh, ushort* __restrict__ Wl) {
  int idx = blockIdx.x*256 + threadIdx.x;
  if (idx >= NFP*K1P) return;
  int n = idx / K1P, k = idx % K1P;
  float v = (n < NF && k < K1) ? Wf1[n*K1 + k] : 0.f;
  ushort h = f2bf(v);
  Wh[idx] = h;
  Wl[idx] = f2bf(v - bf2f(h));
}

// ---------------- GEMM1: h1 = relu(xs @ Wf1^T + bf1) via split-bf16 MFMA ----------------
__global__ __launch_bounds__(256) void gemm1_split(
    const float* __restrict__ xs, const ushort* __restrict__ Wh,
    const ushort* __restrict__ Wl, const float* __restrict__ bias,
    float* __restrict__ h1) {
  __shared__ float Asf[32*36];
  const int tid = threadIdx.x;
  const int wv = tid >> 6, lane = tid & 63;
  const int c = lane & 15, g = lane >> 4;
  const int row0 = blockIdx.x * 32;
  const int ntc = (wv < 2) ? 3 : 2;
  const int ntv[3] = {wv, wv + 4, wv + 8};

  f32x4 acc[3][2];
#pragma unroll
  for (int t = 0; t < 3; ++t)
#pragma unroll
    for (int rt = 0; rt < 2; ++rt) acc[t][rt] = (f32x4){0.f,0.f,0.f,0.f};

  const int srow = tid >> 3;
  const int skof = (tid & 7) * 4;

  for (int ks = 0; ks < K1P/32; ++ks) {
    const int k0 = ks * 32;
    const int ksrc = k0 + skof;
    const float4 av = *(const float4*)&xs[(size_t)(row0 + srow)*K1 + ((ksrc < K1) ? ksrc : 0)];
    __syncthreads();
    *(float4*)&Asf[srow*36 + skof] = av;
    __syncthreads();
    short8v ah[2], al[2];
#pragma unroll
    for (int rt = 0; rt < 2; ++rt) {
      const float* ap = &Asf[(rt*16 + c)*36 + g*8];
      float4 x0 = *(const float4*)ap;
      float4 x1 = *(const float4*)(ap + 4);
      float xv[8] = {x0.x,x0.y,x0.z,x0.w,x1.x,x1.y,x1.z,x1.w};
#pragma unroll
      for (int j = 0; j < 8; ++j) {
        ushort hh = f2bf(xv[j]);
        ah[rt][j] = (short)hh;
        al[rt][j] = (short)f2bf(xv[j] - bf2f(hh));
      }
    }
#pragma unroll
    for (int t = 0; t < 3; ++t) {
      if (t >= ntc) break;
      const int n = ntv[t]*16 + c;
      const size_t wo = (size_t)n*K1P + k0 + g*8;
      short8v wh = *(const short8v*)&Wh[wo];
      short8v wl = *(const short8v*)&Wl[wo];
#pragma unroll
      for (int rt = 0; rt < 2; ++rt) {
        acc[t][rt] = __builtin_amdgcn_mfma_f32_16x16x32_bf16(ah[rt], wh, acc[t][rt], 0, 0, 0);
        acc[t][rt] = __builtin_amdgcn_mfma_f32_16x16x32_bf16(ah[rt], wl, acc[t][rt], 0, 0, 0);
        acc[t][rt] = __builtin_amdgcn_mfma_f32_16x16x32_bf16(al[rt], wh, acc[t][rt], 0, 0, 0);
      }
    }
  }
#pragma unroll
  for (int t = 0; t < 3; ++t) {
    if (t >= ntc) break;
    const int n = ntv[t]*16 + c;
    if (n < NF) {
      const float bv = bias[n];
#pragma unroll
      for (int rt = 0; rt < 2; ++rt)
#pragma unroll
        for (int r = 0; r < 4; ++r) {
          int m = row0 + rt*16 + g*4 + r;
          h1[(size_t)m*NF + n] = fmaxf(acc[t][rt][r] + bv, 0.f);
        }
    }
  }
}

// ---------------- persistent MFMA iteration kernel (DMA Phase A + time-rotated streams) ----------------
// 256 blocks x 512 threads (8 waves); 32 rows/block; 1 block/CU (LDS ~156KB).
// R12 structure + PER-BLOCK TIME ROTATION of the chunk order (Phase A) and
// k-batch order (Phase B): all 256 blocks previously read the same weight
// lines at the same time slot (barrier-locked) -> 32-way same-line L2 queuing
// per XCD. rotA/rotB shift each block's schedule so a given line is touched
// at 8 different time slots across same-XCD blocks. Zero in-loop register
// cost: per-chunk scalar bases only; all register arrays statically indexed
// (wg2own content pre-rotated at init).
__global__ __launch_bounds__(512, 2) void spen_iter_mfma(
    const float* __restrict__ logits,
    const ushort* __restrict__ Wg1b,
    const ushort* __restrict__ Wg1Tb,
    const float* __restrict__ Wg2,
    float* __restrict__ out) {
  __shared__ __align__(16) ushort ring[2][20480];   // 2 x 40KB chunk buffers
  __shared__ ushort p1b[MROWS*PBS];
  __shared__ ushort s_b[MROWS*SBS];
  __shared__ float  u_s[NLBL];

  const int tid  = threadIdx.x;
  const int wv   = tid >> 6;
  const int lane = tid & 63;
  const int col  = lane & 15;
  const int kg   = lane >> 4;
  const int row0 = blockIdx.x * MROWS;
  const int rotA = (int)((blockIdx.x >> 3) & 7u);          // Phase A chunk rotation
  const int rotB = (int)(((blockIdx.x >> 3) * 5u) & 7u);   // Phase B batch rotation

  // ---- pred0 via threefry (p0 = u, p1 = 1-u), bit-exact vs jax ----
  if (tid < NLBL) {
    unsigned i = 3u*(unsigned)tid + 1u;
    unsigned x0, x1; bool use1;
    if (i < 239u) { x0 = i; x1 = (i == 238u) ? 0u : (239u + i); use1 = false; }
    else          { x0 = i - 239u; x1 = i; use1 = true; }
    unsigned o0, o1;
    threefry2x32(0u, 1u, x0, x1, &o0, &o1);
    unsigned bits = use1 ? o1 : o0;
    u_s[tid] = __uint_as_float((bits >> 9) | 0x3f800000u) - 1.0f;
  }
  __syncthreads();
  for (int idx = tid; idx < MROWS*NLP; idx += 512) {
    int m = idx / NLP, l = idx % NLP;
    float p1 = (l < NLBL) ? (1.0f - u_s[l]) : 0.f;
    p1b[m*PBS + l] = f2bf(p1);
  }

  // ---- ownership ----
  const bool has2 = (wv < 2);
  const int l0 = wv*16 + col;            // 0..127
  const int l1 = 128 + wv*16 + col;      // 128..159; l1==159 invalid
  const bool v1 = has2 && (l1 < NLBL);

  // ---- q-state init ----
  float q0[8], q1[8];
  {
    float u0v = u_s[l0];
    float qi0 = __logf((1.0f - u0v) * rcpf(u0v));
    float qi1 = 0.f;
    if (v1) { float u1v = u_s[l1]; qi1 = __logf((1.0f - u1v) * rcpf(u1v)); }
#pragma unroll
    for (int i = 0; i < 8; ++i) { q0[i] = qi0; q1[i] = qi1; }
  }

  // ---- Wg2 preload: statically indexed by TIME step, content pre-rotated ----
  float wg2own[8];
#pragma unroll
  for (int c = 0; c < 8; ++c) {
    const int cc = (c + rotA) & 7;
    wg2own[c] = Wg2[cc*128 + wv*16 + col];
  }

  float lg0[8], lg1[8];
#pragma unroll
  for (int rh = 0; rh < 2; ++rh)
#pragma unroll
    for (int r = 0; r < 4; ++r) {
      int m = row0 + rh*16 + kg*4 + r;
      lg0[rh*4+r] = logits[(size_t)m*NLBL + l0];
      lg1[rh*4+r] = v1 ? logits[(size_t)m*NLBL + l1] : 0.f;
    }

  const char* wg1b_bytes = (const char*)Wg1b;
  const ushort* sp0 = &s_b[col*SBS + kg*8];
  const ushort* sp1 = &s_b[(16 + col)*SBS + kg*8];
  const ushort* wt0 = &Wg1Tb[(size_t)l0*HID + kg*8];
  const ushort* wt1 = &Wg1Tb[(size_t)l1*HID + kg*8];

  // ---- prologue: issue rotated chunk 0 DMA (iter-top barrier will drain it) ----
  {
    const char* g = wg1b_bytes + (size_t)rotA*40960 + wv*5120 + lane*16;
#pragma unroll
    for (int i = 0; i < 5; ++i)
      dma16(g + i*1024, (char*)&ring[0][wv*2560] + i*1024);
  }

  for (int it = 1; it <= 19; ++it) {
    const float lr = rsqrtf((float)it);
    __syncthreads();            // p1b stable; drains vmcnt -> chunk 0 ready
    // ---------------- Phase A: 8 DMA-staged chunks, rotated order ----------------
    short8v afr0[5], afr1[5];
#pragma unroll
    for (int kk = 0; kk < 5; ++kk) {
      afr0[kk] = *(const short8v*)&p1b[col*PBS + kk*32 + kg*8];
      afr1[kk] = *(const short8v*)&p1b[(16 + col)*PBS + kk*32 + kg*8];
    }
#pragma unroll
    for (int c = 0; c < 8; ++c) {
      const int cc = (c + rotA) & 7;     // data chunk processed at time slot c
      if (c < 7) {
        const int cn = (c + 1 + rotA) & 7;
        const char* g = wg1b_bytes + (size_t)cn*40960 + wv*5120 + lane*16;
        char* l = (char*)&ring[(c+1)&1][wv*2560];
#pragma unroll
        for (int i = 0; i < 5; ++i)
          dma16(g + i*1024, l + i*1024);
        asm volatile("s_waitcnt vmcnt(5)" ::: "memory");
      } else {
        asm volatile("s_waitcnt vmcnt(0)" ::: "memory");
      }
      __builtin_amdgcn_sched_barrier(0);
      // compute h-tile (cc*8 + wv) from ring[c&1] rows [wv*16, wv*16+16)
      const ushort* wtile = &ring[c&1][wv*2560];
      f32x4 a0 = (f32x4){0.f,0.f,0.f,0.f};
      f32x4 a1 = (f32x4){0.f,0.f,0.f,0.f};
#pragma unroll
      for (int kk = 0; kk < 5; ++kk) {
        short8v bf = *(const short8v*)&wtile[col*160 + kk*32 + kg*8];
        a0 = __builtin_amdgcn_mfma_f32_16x16x32_bf16(afr0[kk], bf, a0, 0, 0, 0);
        a1 = __builtin_amdgcn_mfma_f32_16x16x32_bf16(afr1[kk], bf, a1, 0, 0, 0);
      }
      const int h = cc*128 + wv*16 + col;
      const float g2 = wg2own[c];
#pragma unroll
      for (int r = 0; r < 4; ++r) {
        s_b[(kg*4 + r)*SBS + h]      = f2bf(g2 * sigmoidf(a0[r]));
        s_b[(16 + kg*4 + r)*SBS + h] = f2bf(g2 * sigmoidf(a1[r]));
      }
    }
    // owners: prefetch Phase-B weight batch 0 (rotated), drained by the barrier
    short8v wrA[2][4], wrB[2][4];
    {
      const int bb0 = rotB;
#pragma unroll
      for (int j = 0; j < 4; ++j) wrA[0][j] = *(const short8v*)(wt0 + (bb0*4 + j)*32);
      if (has2) {
#pragma unroll
        for (int j = 0; j < 4; ++j) wrB[0][j] = *(const short8v*)(wt1 + (bb0*4 + j)*32);
      }
    }
    __syncthreads();            // s_b complete (drains all vmem)
    // issue next iteration's rotated chunk 0 (lands during Phase B)
    if (it < 19) {
      const char* g = wg1b_bytes + (size_t)rotA*40960 + wv*5120 + lane*16;
#pragma unroll
      for (int i = 0; i < 5; ++i)
        dma16(g + i*1024, (char*)&ring[0][wv*2560] + i*1024);
    }
    // ---------------- Phase B: back = s @ Wg1, 8 rotated batches of 4 ksteps ----------------
    f32x4 bA0 = (f32x4){0.f,0.f,0.f,0.f};
    f32x4 bA1 = (f32x4){0.f,0.f,0.f,0.f};
    f32x4 bB0 = (f32x4){0.f,0.f,0.f,0.f};
    f32x4 bB1 = (f32x4){0.f,0.f,0.f,0.f};
    if (has2) {
#pragma unroll
      for (int b = 0; b < 8; ++b) {
        const int cur = b & 1;
        if (b < 7) {
          const int bn = (b + 1 + rotB) & 7;
#pragma unroll
          for (int j = 0; j < 4; ++j) {
            wrA[cur^1][j] = *(const short8v*)(wt0 + (bn*4 + j)*32);
            wrB[cur^1][j] = *(const short8v*)(wt1 + (bn*4 + j)*32);
          }
        }
        const int bb = (b + rotB) & 7;
#pragma unroll
        for (int j = 0; j < 4; ++j) {
          const int kk = bb*4 + j;
          short8v a0 = *(const short8v*)(sp0 + kk*32);
          short8v a1 = *(const short8v*)(sp1 + kk*32);
          bA0 = __builtin_amdgcn_mfma_f32_16x16x32_bf16(a0, wrA[cur][j], bA0, 0, 0, 0);
          bA1 = __builtin_amdgcn_mfma_f32_16x16x32_bf16(a1, wrA[cur][j], bA1, 0, 0, 0);
          bB0 = __builtin_amdgcn_mfma_f32_16x16x32_bf16(a0, wrB[cur][j], bB0, 0, 0, 0);
          bB1 = __builtin_amdgcn_mfma_f32_16x16x32_bf16(a1, wrB[cur][j], bB1, 0, 0, 0);
        }
      }
    } else {
#pragma unroll
      for (int b = 0; b < 8; ++b) {
        const int cur = b & 1;
        if (b < 7) {
          const int bn = (b + 1 + rotB) & 7;
#pragma unroll
          for (int j = 0; j < 4; ++j)
            wrA[cur^1][j] = *(const short8v*)(wt0 + (bn*4 + j)*32);
        }
        const int bb = (b + rotB) & 7;
#pragma unroll
        for (int j = 0; j < 4; ++j) {
          const int kk = bb*4 + j;
          short8v a0 = *(const short8v*)(sp0 + kk*32);
          short8v a1 = *(const short8v*)(sp1 + kk*32);
          bA0 = __builtin_amdgcn_mfma_f32_16x16x32_bf16(a0, wrA[cur][j], bA0, 0, 0, 0);
          bA1 = __builtin_amdgcn_mfma_f32_16x16x32_bf16(a1, wrA[cur][j], bA1, 0, 0, 0);
        }
      }
    }
    // ---------------- update (q-space, owned cells in regs) ----------------
#define UPDATE_ONE(QARR, IDX, LGV, BK, LL, MM)                               \
    {                                                                        \
      float q = QARR[IDX];                                                   \
      float p1v = sigmoidf(q);                                               \
      float p0v = 1.0f - p1v;                                                \
      float rp1 = rcpf(p1v + EPSF);                                          \
      float rp0 = rcpf(p0v + EPSF);                                          \
      float dlt = (LGV) + (BK) - __logf((p1v + EPSF)*rp0) - p1v*rp1 + p0v*rp0;\
      q += lr*dlt;                                                           \
      QARR[IDX] = q;                                                         \
      p1b[(MM)*PBS + (LL)] = f2bf(sigmoidf(q));                              \
    }
#pragma unroll
    for (int r = 0; r < 4; ++r) {
      const int m0r = kg*4 + r;
      UPDATE_ONE(q0, r, lg0[r], bA0[r], l0, m0r)
      const int m1r = 16 + kg*4 + r;
      UPDATE_ONE(q0, 4 + r, lg0[4 + r], bA1[r], l0, m1r)
    }
    if (v1) {
#pragma unroll
      for (int r = 0; r < 4; ++r) {
        const int m0r = kg*4 + r;
        UPDATE_ONE(q1, r, lg1[r], bB0[r], l1, m0r)
        const int m1r = 16 + kg*4 + r;
        UPDATE_ONE(q1, 4 + r, lg1[4 + r], bB1[r], l1, m1r)
      }
    }
#undef UPDATE_ONE
  }

  // ---------------- final write (once) ----------------
#pragma unroll
  for (int rh = 0; rh < 2; ++rh)
#pragma unroll
    for (int r = 0; r < 4; ++r) {
      const int row = row0 + rh*16 + kg*4 + r;
      float p1v = sigmoidf(q0[rh*4 + r]);
      size_t o = ((size_t)row*NLBL + l0)*2;
      out[o]   = 1.0f - p1v;
      out[o+1] = p1v;
      if (v1) {
        float p1w = sigmoidf(q1[rh*4 + r]);
        size_t o2 = ((size_t)row*NLBL + l1)*2;
        out[o2]   = 1.0f - p1w;
        out[o2+1] = p1w;
      }
    }
}

extern "C" void kernel_launch(void* const* d_in, const int* in_sizes, int n_in,
                              void* d_out, int out_size, void* d_ws, size_t ws_size,
                              hipStream_t stream) {
  const float* xs  = (const float*)d_in[0];
  const float* Wf1 = (const float*)d_in[1];
  const float* bf1 = (const float*)d_in[2];
  const float* Wf2 = (const float*)d_in[3];
  const float* bf2 = (const float*)d_in[4];
  const float* Wf3 = (const float*)d_in[5];
  const float* bf3 = (const float*)d_in[6];
  const float* Wg1 = (const float*)d_in[7];
  const float* Wg2 = (const float*)d_in[8];
  float* out = (float*)d_out;

  float* h1     = (float*)d_ws;                 // 8192*150
  float* h2     = h1 + (size_t)BATCH*NF;        // 8192*150
  float* logits = h2 + (size_t)BATCH*NF;        // 8192*159
  ushort* Wg1b  = (ushort*)(logits + (size_t)BATCH*NLBL);  // 1024*160 bf16 (16B-aligned)
  ushort* Wg1Tb = Wg1b + (size_t)HID*NLP;                  // 160*1024 bf16
  ushort* Wf1h  = Wg1Tb + (size_t)NLP*HID;                 // 160*1856 bf16
  ushort* Wf1l  = Wf1h + (size_t)NFP*K1P;                  // 160*1856 bf16

  prep_wf1<<<(NFP*K1P + 255)/256, 256, 0, stream>>>(Wf1, Wf1h, Wf1l);
  prep_weights<<<(HID*NLP + 255)/256, 256, 0, stream>>>(Wg1, Wg1b, Wg1Tb);

  gemm1_split<<<BATCH/32, 256, 0, stream>>>(xs, Wf1h, Wf1l, bf1, h1);
  gemm_xwt<1><<<dim3(BATCH/64, 3), 256, 0, stream>>>(h1, Wf2, bf2, h2, BATCH, NF, NF);
  gemm_xwt<0><<<dim3(BATCH/64, 3), 256, 0, stream>>>(h2, Wf3, bf3, logits, BATCH, NLBL, NF);

  spen_iter_mfma<<<BATCH/MROWS, 512, 0, stream>>>(logits, Wg1b, Wg1Tb, Wg2, out);
}

// Round 14
// 485.196 us; speedup vs baseline: 1.6214x; 1.6214x over previous
//
#include <hip/hip_runtime.h>
#include <hip/hip_bf16.h>
#include <math.h>

#define EPSF 1e-6f
#define NLBL 159
#define NLP  160
#define HID  1024
#define BATCH 8192
#define MROWS 32
#define PBS  168   // ushort row stride p1b
#define SBS  1044  // ushort row stride s_b (522 dw = 10 mod 32 -> conflict-free)
#define K1   1836
#define K1P  1856
#define NF   150
#define NFP  160

typedef __attribute__((ext_vector_type(8))) short short8v;
typedef __attribute__((ext_vector_type(4))) float f32x4;

__device__ inline ushort f2bf(float f) {
  __hip_bfloat16 h = __float2bfloat16(f);
  return *reinterpret_cast<ushort*>(&h);
}
__device__ inline float bf2f(ushort u) {
  unsigned v = ((unsigned)u) << 16;
  return __uint_as_float(v);
}
__device__ inline float rcpf(float x) { return __builtin_amdgcn_rcpf(x); }
__device__ inline float sigmoidf(float x) { return rcpf(1.0f + __expf(-x)); }

// async global->LDS DMA, 16B per lane (wave-uniform LDS base + lane*16)
__device__ __forceinline__ void dma16(const void* g, void* l) {
  __builtin_amdgcn_global_load_lds(
      (const __attribute__((address_space(1))) unsigned int*)g,
      (__attribute__((address_space(3))) unsigned int*)l, 16, 0, 0);
}

// ---------------- threefry2x32 (exact jax semantics, 20 rounds) ----------------
__device__ inline unsigned rotl32(unsigned x, int d){ return (x<<d)|(x>>(32-d)); }

__device__ inline void threefry2x32(unsigned k0, unsigned k1,
                                    unsigned x0, unsigned x1,
                                    unsigned* o0, unsigned* o1) {
  unsigned ks0=k0, ks1=k1, ks2=k0^k1^0x1BD11BDAu;
  x0 += ks0; x1 += ks1;
#define TF_R(r) { x0 += x1; x1 = rotl32(x1,(r)); x1 ^= x0; }
  TF_R(13) TF_R(15) TF_R(26) TF_R(6)  x0 += ks1; x1 += ks2 + 1u;
  TF_R(17) TF_R(29) TF_R(16) TF_R(24) x0 += ks2; x1 += ks0 + 2u;
  TF_R(13) TF_R(15) TF_R(26) TF_R(6)  x0 += ks0; x1 += ks1 + 3u;
  TF_R(17) TF_R(29) TF_R(16) TF_R(24) x0 += ks1; x1 += ks2 + 4u;
  TF_R(13) TF_R(15) TF_R(26) TF_R(6)  x0 += ks2; x1 += ks0 + 5u;
#undef TF_R
  *o0 = x0; *o1 = x1;
}

// ---------------- prep: Wg1 (1024x159 f32) -> Wg1b[1024][160] bf16, Wg1Tb[160][1024] bf16 ----------------
__global__ void prep_weights(const float* __restrict__ Wg1,
                             ushort* __restrict__ Wg1b,
                             ushort* __restrict__ Wg1Tb) {
  int idx = blockIdx.x*256 + threadIdx.x;
  if (idx >= HID*NLP) return;
  int h = idx / NLP, l = idx % NLP;
  float v = (l < NLBL) ? Wg1[h*NLBL + l] : 0.f;
  ushort b = f2bf(v);
  Wg1b[h*NLP + l]  = b;
  Wg1Tb[l*HID + h] = b;
}

// ---------------- prep: Wf1 (150x1836 f32) -> split hi/lo bf16, padded [160][1856] ----------------
__global__ void prep_wf1(const float* __restrict__ Wf1,
                         ushort* __restrict__ Wh, ushort* __restrict__ Wl) {
  int idx = blockIdx.x*256 + threadIdx.x;
  if (idx >= NFP*K1P) return;
  int n = idx / K1P, k = idx % K1P;
  float v = (n < NF && k < K1) ? Wf1[n*K1 + k] : 0.f;
  ushort h = f2bf(v);
  Wh[idx] = h;
  Wl[idx] = f2bf(v - bf2f(h));
}

// ---------------- prep: Wf2 (150x150), Wf3 (159x150) -> split hi/lo bf16 padded [160][160] ----------------
__global__ void prep_w23(const float* __restrict__ Wf2, const float* __restrict__ Wf3,
                         ushort* __restrict__ W2h, ushort* __restrict__ W2l,
                         ushort* __restrict__ W3h, ushort* __restrict__ W3l) {
  int idx = blockIdx.x*256 + threadIdx.x;
  if (idx >= NFP*NFP) return;
  int n = idx / NFP, k = idx % NFP;
  float v2 = (n < NF && k < NF) ? Wf2[n*NF + k] : 0.f;
  ushort h2 = f2bf(v2);
  W2h[idx] = h2; W2l[idx] = f2bf(v2 - bf2f(h2));
  float v3 = (n < NLBL && k < NF) ? Wf3[n*NF + k] : 0.f;
  ushort h3 = f2bf(v3);
  W3h[idx] = h3; W3l[idx] = f2bf(v3 - bf2f(h3));
}

// ---------------- fused MLP: logits = (relu(relu(xs@W1^T+b1)@W2^T+b2))@W3^T+b3 ----------------
// 256 blocks x 256 thr (4 waves); 32 rows/block; split-bf16 MFMA throughout.
// h1, h2 kept in LDS (split hi/lo) -> no global round trips, 1 launch for 3 layers.
__global__ __launch_bounds__(256) void mlp_fused(
    const float* __restrict__ xs,
    const ushort* __restrict__ W1h, const ushort* __restrict__ W1l, const float* __restrict__ b1,
    const ushort* __restrict__ W2h, const ushort* __restrict__ W2l, const float* __restrict__ b2,
    const ushort* __restrict__ W3h, const ushort* __restrict__ W3l, const float* __restrict__ b3,
    float* __restrict__ logits) {
  __shared__ float Asf[32*36];
  __shared__ ushort h1h[32*168], h1l[32*168];
  __shared__ ushort h2h[32*168], h2l[32*168];
  const int tid = threadIdx.x;
  const int wv = tid >> 6, lane = tid & 63;
  const int c = lane & 15, g = lane >> 4;
  const int row0 = blockIdx.x * 32;
  const int ntc = (wv < 2) ? 3 : 2;
  const int ntv[3] = {wv, wv + 4, wv + 8};

  // ================= Layer 1: K=1856 (global staging) =================
  f32x4 acc[3][2];
#pragma unroll
  for (int t = 0; t < 3; ++t)
#pragma unroll
    for (int rt = 0; rt < 2; ++rt) acc[t][rt] = (f32x4){0.f,0.f,0.f,0.f};

  const int srow = tid >> 3;
  const int skof = (tid & 7) * 4;

  for (int ks = 0; ks < K1P/32; ++ks) {
    const int k0 = ks * 32;
    const int ksrc = k0 + skof;
    const float4 av = *(const float4*)&xs[(size_t)(row0 + srow)*K1 + ((ksrc < K1) ? ksrc : 0)];
    __syncthreads();
    *(float4*)&Asf[srow*36 + skof] = av;
    __syncthreads();
    short8v ah[2], al[2];
#pragma unroll
    for (int rt = 0; rt < 2; ++rt) {
      const float* ap = &Asf[(rt*16 + c)*36 + g*8];
      float4 x0 = *(const float4*)ap;
      float4 x1 = *(const float4*)(ap + 4);
      float xv[8] = {x0.x,x0.y,x0.z,x0.w,x1.x,x1.y,x1.z,x1.w};
#pragma unroll
      for (int j = 0; j < 8; ++j) {
        ushort hh = f2bf(xv[j]);
        ah[rt][j] = (short)hh;
        al[rt][j] = (short)f2bf(xv[j] - bf2f(hh));
      }
    }
#pragma unroll
    for (int t = 0; t < 3; ++t) {
      if (t >= ntc) break;
      const int n = ntv[t]*16 + c;
      const size_t wo = (size_t)n*K1P + k0 + g*8;
      short8v wh = *(const short8v*)&W1h[wo];
      short8v wl = *(const short8v*)&W1l[wo];
#pragma unroll
      for (int rt = 0; rt < 2; ++rt) {
        acc[t][rt] = __builtin_amdgcn_mfma_f32_16x16x32_bf16(ah[rt], wh, acc[t][rt], 0, 0, 0);
        acc[t][rt] = __builtin_amdgcn_mfma_f32_16x16x32_bf16(ah[rt], wl, acc[t][rt], 0, 0, 0);
        acc[t][rt] = __builtin_amdgcn_mfma_f32_16x16x32_bf16(al[rt], wh, acc[t][rt], 0, 0, 0);
      }
    }
  }
  // epilogue L1 -> h1 LDS (split hi/lo); n>=150 zeroed (pad cols annihilated by zero W2 pad)
  __syncthreads();
#pragma unroll
  for (int t = 0; t < 3; ++t) {
    if (t >= ntc) break;
    const int n = ntv[t]*16 + c;
    const float bv = (n < NF) ? b1[n] : 0.f;
#pragma unroll
    for (int rt = 0; rt < 2; ++rt)
#pragma unroll
      for (int r = 0; r < 4; ++r) {
        const int m = rt*16 + g*4 + r;
        float v = (n < NF) ? fmaxf(acc[t][rt][r] + bv, 0.f) : 0.f;
        ushort hi = f2bf(v);
        h1h[m*168 + n] = hi;
        h1l[m*168 + n] = f2bf(v - bf2f(hi));
      }
  }
  __syncthreads();

  // ================= Layer 2: K=160 (A from h1 LDS) =================
  f32x4 a2[3][2];
#pragma unroll
  for (int t = 0; t < 3; ++t)
#pragma unroll
    for (int rt = 0; rt < 2; ++rt) a2[t][rt] = (f32x4){0.f,0.f,0.f,0.f};
#pragma unroll
  for (int kk = 0; kk < 5; ++kk) {
    short8v ah[2], al[2];
#pragma unroll
    for (int rt = 0; rt < 2; ++rt) {
      ah[rt] = *(const short8v*)&h1h[(rt*16 + c)*168 + kk*32 + g*8];
      al[rt] = *(const short8v*)&h1l[(rt*16 + c)*168 + kk*32 + g*8];
    }
#pragma unroll
    for (int t = 0; t < 3; ++t) {
      if (t >= ntc) break;
      const int n = ntv[t]*16 + c;
      const size_t wo = (size_t)n*NFP + kk*32 + g*8;
      short8v wh = *(const short8v*)&W2h[wo];
      short8v wl = *(const short8v*)&W2l[wo];
#pragma unroll
      for (int rt = 0; rt < 2; ++rt) {
        a2[t][rt] = __builtin_amdgcn_mfma_f32_16x16x32_bf16(ah[rt], wh, a2[t][rt], 0, 0, 0);
        a2[t][rt] = __builtin_amdgcn_mfma_f32_16x16x32_bf16(ah[rt], wl, a2[t][rt], 0, 0, 0);
        a2[t][rt] = __builtin_amdgcn_mfma_f32_16x16x32_bf16(al[rt], wh, a2[t][rt], 0, 0, 0);
      }
    }
  }
#pragma unroll
  for (int t = 0; t < 3; ++t) {
    if (t >= ntc) break;
    const int n = ntv[t]*16 + c;
    const float bv = (n < NF) ? b2[n] : 0.f;
#pragma unroll
    for (int rt = 0; rt < 2; ++rt)
#pragma unroll
      for (int r = 0; r < 4; ++r) {
        const int m = rt*16 + g*4 + r;
        float v = (n < NF) ? fmaxf(a2[t][rt][r] + bv, 0.f) : 0.f;
        ushort hi = f2bf(v);
        h2h[m*168 + n] = hi;
        h2l[m*168 + n] = f2bf(v - bf2f(hi));
      }
  }
  __syncthreads();

  // ================= Layer 3: K=160 (A from h2 LDS) -> logits global =================
  f32x4 a3[3][2];
#pragma unroll
  for (int t = 0; t < 3; ++t)
#pragma unroll
    for (int rt = 0; rt < 2; ++rt) a3[t][rt] = (f32x4){0.f,0.f,0.f,0.f};
#pragma unroll
  for (int kk = 0; kk < 5; ++kk) {
    short8v ah[2], al[2];
#pragma unroll
    for (int rt = 0; rt < 2; ++rt) {
      ah[rt] = *(const short8v*)&h2h[(rt*16 + c)*168 + kk*32 + g*8];
      al[rt] = *(const short8v*)&h2l[(rt*16 + c)*168 + kk*32 + g*8];
    }
#pragma unroll
    for (int t = 0; t < 3; ++t) {
      if (t >= ntc) break;
      const int n = ntv[t]*16 + c;
      const size_t wo = (size_t)n*NFP + kk*32 + g*8;
      short8v wh = *(const short8v*)&W3h[wo];
      short8v wl = *(const short8v*)&W3l[wo];
#pragma unroll
      for (int rt = 0; rt < 2; ++rt) {
        a3[t][rt] = __builtin_amdgcn_mfma_f32_16x16x32_bf16(ah[rt], wh, a3[t][rt], 0, 0, 0);
        a3[t][rt] = __builtin_amdgcn_mfma_f32_16x16x32_bf16(ah[rt], wl, a3[t][rt], 0, 0, 0);
        a3[t][rt] = __builtin_amdgcn_mfma_f32_16x16x32_bf16(al[rt], wh, a3[t][rt], 0, 0, 0);
      }
    }
  }
#pragma unroll
  for (int t = 0; t < 3; ++t) {
    if (t >= ntc) break;
    const int n = ntv[t]*16 + c;
    if (n < NLBL) {
      const float bv = b3[n];
#pragma unroll
      for (int rt = 0; rt < 2; ++rt)
#pragma unroll
        for (int r = 0; r < 4; ++r) {
          const int m = row0 + rt*16 + g*4 + r;
          logits[(size_t)m*NLBL + n] = a3[t][rt][r] + bv;
        }
    }
  }
}

// ---------------- persistent MFMA iteration kernel (q-space, DMA-staged Phase A) ----------------
// EXACT R12 structure (best clean state: 407us, FETCH 5.2MB, WRITE 10.2MB, no spills).
// 256 blocks x 512 threads (8 waves); 32 rows/block; 1 block/CU (LDS ~156KB).
// Phase A: Wg1b streamed via global_load_lds in 8 chunks of 128 h-rows (40KB),
//          double-buffered ring; wave w stages ITS OWN 5KB slice, counted vmcnt.
// Phase B: VGPR weight loads, 1-deep dbuf, 8 batches of 4 k-steps.
__global__ __launch_bounds__(512, 2) void spen_iter_mfma(
    const float* __restrict__ logits,
    const ushort* __restrict__ Wg1b,
    const ushort* __restrict__ Wg1Tb,
    const float* __restrict__ Wg2,
    float* __restrict__ out) {
  __shared__ __align__(16) ushort ring[2][20480];   // 2 x 40KB chunk buffers
  __shared__ ushort p1b[MROWS*PBS];
  __shared__ ushort s_b[MROWS*SBS];
  __shared__ float  u_s[NLBL];

  const int tid  = threadIdx.x;
  const int wv   = tid >> 6;
  const int lane = tid & 63;
  const int col  = lane & 15;
  const int kg   = lane >> 4;
  const int row0 = blockIdx.x * MROWS;

  // ---- pred0 via threefry (p0 = u, p1 = 1-u), bit-exact vs jax ----
  if (tid < NLBL) {
    unsigned i = 3u*(unsigned)tid + 1u;
    unsigned x0, x1; bool use1;
    if (i < 239u) { x0 = i; x1 = (i == 238u) ? 0u : (239u + i); use1 = false; }
    else          { x0 = i - 239u; x1 = i; use1 = true; }
    unsigned o0, o1;
    threefry2x32(0u, 1u, x0, x1, &o0, &o1);
    unsigned bits = use1 ? o1 : o0;
    u_s[tid] = __uint_as_float((bits >> 9) | 0x3f800000u) - 1.0f;
  }
  __syncthreads();
  for (int idx = tid; idx < MROWS*NLP; idx += 512) {
    int m = idx / NLP, l = idx % NLP;
    float p1 = (l < NLBL) ? (1.0f - u_s[l]) : 0.f;
    p1b[m*PBS + l] = f2bf(p1);
  }

  // ---- ownership ----
  const bool has2 = (wv < 2);
  const int l0 = wv*16 + col;            // 0..127
  const int l1 = 128 + wv*16 + col;      // 128..159; l1==159 invalid
  const bool v1 = has2 && (l1 < NLBL);

  // ---- q-state init ----
  float q0[8], q1[8];
  {
    float u0v = u_s[l0];
    float qi0 = __logf((1.0f - u0v) * rcpf(u0v));
    float qi1 = 0.f;
    if (v1) { float u1v = u_s[l1]; qi1 = __logf((1.0f - u1v) * rcpf(u1v)); }
#pragma unroll
    for (int i = 0; i < 8; ++i) { q0[i] = qi0; q1[i] = qi1; }
  }

  // ---- constant preloads: Wg2 per chunk (wave w owns h-tile c*8+w) ----
  float wg2own[8];
#pragma unroll
  for (int c = 0; c < 8; ++c) wg2own[c] = Wg2[(c*8 + wv)*16 + col];

  float lg0[8], lg1[8];
#pragma unroll
  for (int rh = 0; rh < 2; ++rh)
#pragma unroll
    for (int r = 0; r < 4; ++r) {
      int m = row0 + rh*16 + kg*4 + r;
      lg0[rh*4+r] = logits[(size_t)m*NLBL + l0];
      lg1[rh*4+r] = v1 ? logits[(size_t)m*NLBL + l1] : 0.f;
    }

  const char* wg1b_bytes = (const char*)Wg1b;
  const ushort* sp0 = &s_b[col*SBS + kg*8];
  const ushort* sp1 = &s_b[(16 + col)*SBS + kg*8];
  const ushort* wt0 = &Wg1Tb[(size_t)l0*HID + kg*8];
  const ushort* wt1 = &Wg1Tb[(size_t)l1*HID + kg*8];

  // ---- prologue: issue chunk 0 DMA (iter-top barrier will drain it) ----
  {
    const char* g = wg1b_bytes + wv*5120 + lane*16;
#pragma unroll
    for (int i = 0; i < 5; ++i)
      dma16(g + i*1024, (char*)&ring[0][wv*2560] + i*1024);
  }

  for (int it = 1; it <= 19; ++it) {
    const float lr = rsqrtf((float)it);
    __syncthreads();            // p1b stable; drains vmcnt -> chunk 0 ready
    // ---------------- Phase A: 8 DMA-staged chunks ----------------
    short8v afr0[5], afr1[5];
#pragma unroll
    for (int kk = 0; kk < 5; ++kk) {
      afr0[kk] = *(const short8v*)&p1b[col*PBS + kk*32 + kg*8];
      afr1[kk] = *(const short8v*)&p1b[(16 + col)*PBS + kk*32 + kg*8];
    }
#pragma unroll
    for (int c = 0; c < 8; ++c) {
      if (c < 7) {
        // stage own 5KB slice of chunk c+1
        const char* g = wg1b_bytes + (size_t)(c+1)*40960 + wv*5120 + lane*16;
        char* l = (char*)&ring[(c+1)&1][wv*2560];
#pragma unroll
        for (int i = 0; i < 5; ++i)
          dma16(g + i*1024, l + i*1024);
        asm volatile("s_waitcnt vmcnt(5)" ::: "memory");
      } else {
        asm volatile("s_waitcnt vmcnt(0)" ::: "memory");
      }
      __builtin_amdgcn_sched_barrier(0);
      // compute h-tile (c*8 + wv) from ring[c&1] rows [wv*16, wv*16+16)
      const ushort* wtile = &ring[c&1][wv*2560];
      f32x4 a0 = (f32x4){0.f,0.f,0.f,0.f};
      f32x4 a1 = (f32x4){0.f,0.f,0.f,0.f};
#pragma unroll
      for (int kk = 0; kk < 5; ++kk) {
        short8v bf = *(const short8v*)&wtile[col*160 + kk*32 + kg*8];
        a0 = __builtin_amdgcn_mfma_f32_16x16x32_bf16(afr0[kk], bf, a0, 0, 0, 0);
        a1 = __builtin_amdgcn_mfma_f32_16x16x32_bf16(afr1[kk], bf, a1, 0, 0, 0);
      }
      const int h = c*128 + wv*16 + col;
      const float g2 = wg2own[c];
#pragma unroll
      for (int r = 0; r < 4; ++r) {
        s_b[(kg*4 + r)*SBS + h]      = f2bf(g2 * sigmoidf(a0[r]));
        s_b[(16 + kg*4 + r)*SBS + h] = f2bf(g2 * sigmoidf(a1[r]));
      }
    }
    // owners: prefetch Phase-B weight batch 0 (drained by the barrier)
    short8v wrA[2][4], wrB[2][4];
#pragma unroll
    for (int j = 0; j < 4; ++j) wrA[0][j] = *(const short8v*)(wt0 + j*32);
    if (has2) {
#pragma unroll
      for (int j = 0; j < 4; ++j) wrB[0][j] = *(const short8v*)(wt1 + j*32);
    }
    __syncthreads();            // s_b complete (drains all vmem)
    // issue next iteration's chunk 0 (lands during Phase B)
    if (it < 19) {
      const char* g = wg1b_bytes + wv*5120 + lane*16;
#pragma unroll
      for (int i = 0; i < 5; ++i)
        dma16(g + i*1024, (char*)&ring[0][wv*2560] + i*1024);
    }
    // ---------------- Phase B: back = s @ Wg1, 8 batches of 4 ksteps ----------------
    f32x4 bA0 = (f32x4){0.f,0.f,0.f,0.f};
    f32x4 bA1 = (f32x4){0.f,0.f,0.f,0.f};
    f32x4 bB0 = (f32x4){0.f,0.f,0.f,0.f};
    f32x4 bB1 = (f32x4){0.f,0.f,0.f,0.f};
    if (has2) {
#pragma unroll
      for (int b = 0; b < 8; ++b) {
        const int cur = b & 1;
        if (b < 7) {
#pragma unroll
          for (int j = 0; j < 4; ++j) {
            wrA[cur^1][j] = *(const short8v*)(wt0 + ((b+1)*4 + j)*32);
            wrB[cur^1][j] = *(const short8v*)(wt1 + ((b+1)*4 + j)*32);
          }
        }
#pragma unroll
        for (int j = 0; j < 4; ++j) {
          const int kk = b*4 + j;
          short8v a0 = *(const short8v*)(sp0 + kk*32);
          short8v a1 = *(const short8v*)(sp1 + kk*32);
          bA0 = __builtin_amdgcn_mfma_f32_16x16x32_bf16(a0, wrA[cur][j], bA0, 0, 0, 0);
          bA1 = __builtin_amdgcn_mfma_f32_16x16x32_bf16(a1, wrA[cur][j], bA1, 0, 0, 0);
          bB0 = __builtin_amdgcn_mfma_f32_16x16x32_bf16(a0, wrB[cur][j], bB0, 0, 0, 0);
          bB1 = __builtin_amdgcn_mfma_f32_16x16x32_bf16(a1, wrB[cur][j], bB1, 0, 0, 0);
        }
      }
    } else {
#pragma unroll
      for (int b = 0; b < 8; ++b) {
        const int cur = b & 1;
        if (b < 7) {
#pragma unroll
          for (int j = 0; j < 4; ++j)
            wrA[cur^1][j] = *(const short8v*)(wt0 + ((b+1)*4 + j)*32);
        }
#pragma unroll
        for (int j = 0; j < 4; ++j) {
          const int kk = b*4 + j;
          short8v a0 = *(const short8v*)(sp0 + kk*32);
          short8v a1 = *(const short8v*)(sp1 + kk*32);
          bA0 = __builtin_amdgcn_mfma_f32_16x16x32_bf16(a0, wrA[cur][j], bA0, 0, 0, 0);
          bA1 = __builtin_amdgcn_mfma_f32_16x16x32_bf16(a1, wrA[cur][j], bA1, 0, 0, 0);
        }
      }
    }
    // ---------------- update (q-space, owned cells in regs) ----------------
#define UPDATE_ONE(QARR, IDX, LGV, BK, LL, MM)                               \
    {                                                                        \
      float q = QARR[IDX];                                                   \
      float p1v = sigmoidf(q);                                               \
      float p0v = 1.0f - p1v;                                                \
      float rp1 = rcpf(p1v + EPSF);                                          \
      float rp0 = rcpf(p0v + EPSF);                                          \
      float dlt = (LGV) + (BK) - __logf((p1v + EPSF)*rp0) - p1v*rp1 + p0v*rp0;\
      q += lr*dlt;                                                           \
      QARR[IDX] = q;                                                         \
      p1b[(MM)*PBS + (LL)] = f2bf(sigmoidf(q));                              \
    }
#pragma unroll
    for (int r = 0; r < 4; ++r) {
      const int m0r = kg*4 + r;
      UPDATE_ONE(q0, r, lg0[r], bA0[r], l0, m0r)
      const int m1r = 16 + kg*4 + r;
      UPDATE_ONE(q0, 4 + r, lg0[4 + r], bA1[r], l0, m1r)
    }
    if (v1) {
#pragma unroll
      for (int r = 0; r < 4; ++r) {
        const int m0r = kg*4 + r;
        UPDATE_ONE(q1, r, lg1[r], bB0[r], l1, m0r)
        const int m1r = 16 + kg*4 + r;
        UPDATE_ONE(q1, 4 + r, lg1[4 + r], bB1[r], l1, m1r)
      }
    }
#undef UPDATE_ONE
  }

  // ---------------- final write (once) ----------------
#pragma unroll
  for (int rh = 0; rh < 2; ++rh)
#pragma unroll
    for (int r = 0; r < 4; ++r) {
      const int row = row0 + rh*16 + kg*4 + r;
      float p1v = sigmoidf(q0[rh*4 + r]);
      size_t o = ((size_t)row*NLBL + l0)*2;
      out[o]   = 1.0f - p1v;
      out[o+1] = p1v;
      if (v1) {
        float p1w = sigmoidf(q1[rh*4 + r]);
        size_t o2 = ((size_t)row*NLBL + l1)*2;
        out[o2]   = 1.0f - p1w;
        out[o2+1] = p1w;
      }
    }
}

extern "C" void kernel_launch(void* const* d_in, const int* in_sizes, int n_in,
                              void* d_out, int out_size, void* d_ws, size_t ws_size,
                              hipStream_t stream) {
  const float* xs  = (const float*)d_in[0];
  const float* Wf1 = (const float*)d_in[1];
  const float* bf1 = (const float*)d_in[2];
  const float* Wf2 = (const float*)d_in[3];
  const float* bf2 = (const float*)d_in[4];
  const float* Wf3 = (const float*)d_in[5];
  const float* bf3 = (const float*)d_in[6];
  const float* Wg1 = (const float*)d_in[7];
  const float* Wg2 = (const float*)d_in[8];
  float* out = (float*)d_out;

  float* logits = (float*)d_ws;                             // 8192*159 f32
  ushort* Wg1b  = (ushort*)(logits + (size_t)BATCH*NLBL);   // 1024*160 bf16 (16B-aligned)
  ushort* Wg1Tb = Wg1b + (size_t)HID*NLP;                   // 160*1024 bf16
  ushort* Wf1h  = Wg1Tb + (size_t)NLP*HID;                  // 160*1856 bf16
  ushort* Wf1l  = Wf1h + (size_t)NFP*K1P;                   // 160*1856 bf16
  ushort* Wf2h  = Wf1l + (size_t)NFP*K1P;                   // 160*160 bf16
  ushort* Wf2l  = Wf2h + (size_t)NFP*NFP;
  ushort* Wf3h  = Wf2l + (size_t)NFP*NFP;
  ushort* Wf3l  = Wf3h + (size_t)NFP*NFP;

  prep_wf1<<<(NFP*K1P + 255)/256, 256, 0, stream>>>(Wf1, Wf1h, Wf1l);
  prep_w23<<<(NFP*NFP + 255)/256, 256, 0, stream>>>(Wf2, Wf3, Wf2h, Wf2l, Wf3h, Wf3l);
  prep_weights<<<(HID*NLP + 255)/256, 256, 0, stream>>>(Wg1, Wg1b, Wg1Tb);

  mlp_fused<<<BATCH/32, 256, 0, stream>>>(xs, Wf1h, Wf1l, bf1,
                                          Wf2h, Wf2l, bf2,
                                          Wf3h, Wf3l, bf3, logits);

  spen_iter_mfma<<<BATCH/MROWS, 512, 0, stream>>>(logits, Wg1b, Wg1Tb, Wg2, out);
}